// Round 7
// baseline (371.831 us; speedup 1.0000x reference)
//
#include <hip/hip_runtime.h>
#include <math.h>

#define BATCH 1024
#define SEQ   200
#define DIN   128
#define DOUT  128
#define GSTR  260    // k_iter LDS u32 stride per 8-row group (256 data + 4 pad)
#define PSTR  608    // partial-delta row stride (floats)

typedef __attribute__((ext_vector_type(8))) short short8;
typedef __attribute__((ext_vector_type(4))) float f32x4;

// async global->LDS, 16B per lane; LDS dest = wave-uniform base + lane*16
__device__ __forceinline__ void async_copy16(const void* g, void* l) {
    __builtin_amdgcn_global_load_lds((const __attribute__((address_space(1))) void*)g,
                                     (__attribute__((address_space(3))) void*)l,
                                     16, 0, 0);
}

// fp32 -> packed (bf16_hi << 16) | bf16_lo ; hi = round-half-up, lo = RTZ residual
__device__ __forceinline__ unsigned pack_split(float f) {
    unsigned u = __float_as_uint(f);
    unsigned r = u + 0x8000u;
    unsigned hi = r >> 16;
    float hf = __uint_as_float(r & 0xffff0000u);
    unsigned lo = __float_as_uint(f - hf) >> 16;
    return (hi << 16) | lo;
}

__device__ __forceinline__ void split2(float f, short& h, short& l) {
    unsigned u = __float_as_uint(f);
    unsigned r = u + 0x8000u;
    h = (short)(r >> 16);
    float hf = __uint_as_float(r & 0xffff0000u);
    l = (short)(__float_as_uint(f - hf) >> 16);
}

// exact reconstruction of packed value
__device__ __forceinline__ float unpk(unsigned u) {
    return __uint_as_float(u & 0xffff0000u) + __uint_as_float(u << 16);
}

// ---- pre-split S into MFMA B-fragment order (hi at idx, lo at 16384+idx) ----
__global__ __launch_bounds__(256) void k_presplit(const float* __restrict__ S,
                                                  short* __restrict__ Sp) {
    int g = blockIdx.x * 256 + threadIdx.x;          // 0..16383
    int j = g & 7, lane = (g >> 3) & 63, kt = (g >> 9) & 3, nt = g >> 11;
    int k = kt * 32 + (lane >> 4) * 8 + j;
    int n = nt * 16 + (lane & 15);
    short h, l;
    split2(S[k * DOUT + n], h, l);
    Sp[g] = h;
    Sp[16384 + g] = l;
}

// ---- K1: grid-stride 64-row tiles, register double-buffered A prefetch ----
__global__ __launch_bounds__(256, 2) void k_gemm(const float* __restrict__ A,
                                                 const short* __restrict__ Sp,
                                                 unsigned* __restrict__ outp) {
    __shared__ short sSp[32768];   // 64 KB: hi [0..16383], lo [16384..]
    const int t = threadIdx.x;
    const int w = t >> 6, lane = t & 63;
    const int q = lane >> 4, c = lane & 15;
    const int GD = gridDim.x;
    const int NT = (BATCH * SEQ) / 64;   // 3200

    float4 bA[8], bB[8];

    auto PF = [&](int tile, float4* buf) {
        const float* ap = A + ((long)tile * 64 + w * 16 + c) * DIN + q * 8;
#pragma unroll
        for (int kt = 0; kt < 4; ++kt) {
            buf[2 * kt]     = *(const float4*)(ap + kt * 32);
            buf[2 * kt + 1] = *(const float4*)(ap + kt * 32 + 4);
        }
    };
    auto COMPUTE = [&](int tile, const float4* buf) {
        short8 ah[4], al[4];
#pragma unroll
        for (int kt = 0; kt < 4; ++kt) {
            float av[8];
            *(float4*)&av[0] = buf[2 * kt];
            *(float4*)&av[4] = buf[2 * kt + 1];
#pragma unroll
            for (int j = 0; j < 8; ++j) {
                short h, l;
                split2(av[j], h, l);
                ah[kt][j] = h; al[kt][j] = l;
            }
        }
        f32x4 acc[8];
        const f32x4 zz = {0.f, 0.f, 0.f, 0.f};
#pragma unroll
        for (int nt = 0; nt < 8; ++nt) acc[nt] = zz;
#pragma unroll
        for (int kt = 0; kt < 4; ++kt)
#pragma unroll
            for (int nt = 0; nt < 8; ++nt) {
                const int fo = ((nt * 4 + kt) * 64 + lane) * 8;
                short8 sh = *(const short8*)&sSp[fo];
                short8 sl = *(const short8*)&sSp[16384 + fo];
                acc[nt] = __builtin_amdgcn_mfma_f32_16x16x32_bf16(ah[kt], sh, acc[nt], 0, 0, 0);
                acc[nt] = __builtin_amdgcn_mfma_f32_16x16x32_bf16(al[kt], sh, acc[nt], 0, 0, 0);
                acc[nt] = __builtin_amdgcn_mfma_f32_16x16x32_bf16(ah[kt], sl, acc[nt], 0, 0, 0);
            }
        const long r0 = (long)tile * 64 + w * 16 + q * 4;
#pragma unroll
        for (int nt = 0; nt < 8; ++nt)
#pragma unroll
            for (int r = 0; r < 4; ++r)
                outp[(r0 + r) * DOUT + nt * 16 + c] = pack_split(acc[nt][r]);
    };

    int ti = blockIdx.x;
    PF(ti, bA);
#pragma unroll
    for (int i = 0; i < 16; ++i) {       // async Sp stage (after A-prefetch)
        const int g = w * 16 + i;
        async_copy16(Sp + g * 512 + lane * 8, &sSp[g * 512]);
    }
    __syncthreads();
    int tn = ti + GD;
    for (;;) {
        if (tn < NT) PF(tn, bB);
        COMPUTE(ti, bA);
        ti = tn; tn += GD;
        if (ti >= NT) break;
        if (tn < NT) PF(tn, bA);
        COMPUTE(ti, bB);
        ti = tn; tn += GD;
        if (ti >= NT) break;
    }
}

// ---- K2: routing iteration; task = (b, e-quarter), 2 tasks/block, dbuf async ----
__global__ __launch_bounds__(256, 2) void k_iter(
    const unsigned* __restrict__ lowp,   // [B][200][128] packed hi|lo
    const float* __restrict__ Bm,        // [3][200]
    const int* __restrict__ seq,         // [B]
    const float* __restrict__ acc0, const float* __restrict__ acc1,
    float* __restrict__ part,            // [4096][PSTR]
    float* __restrict__ out, int iter) {
    __shared__ unsigned sLn[2][25 * GSTR];   // 2 x 26 KB, 8-row groups +4 pad
    __shared__ float sW[SEQ * 4];
    __shared__ float pB[4][3][32];
    __shared__ float sH[3][32];

    const int t = threadIdx.x, lane = t & 63, w = t >> 6;

    float r0[4], r1[4], r2[4];   // softmax raw regs (waves 0-2)
    auto RAW = [&](int b) {
        if (w < 3) {
#pragma unroll
            for (int i = 0; i < 4; ++i) {
                int l = lane + 64 * i; bool inb = l < SEQ;
                r0[i] = inb ? Bm[w * SEQ + l] : 0.f;
                r1[i] = (inb && iter >= 1) ? acc0[w * SEQ + l] : 0.f;
                r2[i] = (inb && iter >= 2) ? acc1[w * SEQ + l] : 0.f;
            }
        }
    };
    auto STAGE = [&](int b, int qr, unsigned* sb) {
        const unsigned* lp = lowp + (size_t)b * (SEQ * DIN) + qr * 32;
        for (int g = w; g < 25; g += 4)   // 1KB inst = 8 rows x 32 u32
            async_copy16(lp + (g * 8 + (lane >> 3)) * DIN + (lane & 7) * 4,
                         &sb[g * GSTR]);
    };
    auto FIN = [&](int b) {
        if (w < 3) {
            const int n = seq[b];
            float m = -INFINITY, vv[4];
#pragma unroll
            for (int i = 0; i < 4; ++i) {
                int l = lane + 64 * i;
                float v = r0[i] + r1[i] + r2[i];
                vv[i] = (l < n) ? v : -INFINITY;
                if (l < n) m = fmaxf(m, v);
            }
            for (int off = 32; off; off >>= 1) m = fmaxf(m, __shfl_xor(m, off, 64));
            float s = 0.f, pv[4];
#pragma unroll
            for (int i = 0; i < 4; ++i) {
                pv[i] = (vv[i] == -INFINITY) ? 0.f : expf(vv[i] - m);
                s += pv[i];
            }
            for (int off = 32; off; off >>= 1) s += __shfl_xor(s, off, 64);
            float rs = 1.f / s;
#pragma unroll
            for (int i = 0; i < 4; ++i) {
                int l = lane + 64 * i;
                if (l < SEQ) sW[l * 4 + w] = pv[i] * rs;
            }
        }
    };
    // pass B + cross-wave reduce + squash; ends after its second barrier
    auto CORE_BH = [&](const unsigned* sb, int b, int qr) {
        const int el = t & 31, lg = t >> 5;
        float h0 = 0.f, h1 = 0.f, h2 = 0.f;
#pragma unroll
        for (int i = 0; i < 25; ++i) {
            int l = lg * 25 + i;
            float4 wv = *(const float4*)&sW[l * 4];
            float f = unpk(sb[(l >> 3) * GSTR + (l & 7) * 32 + el]);
            h0 = fmaf(wv.x, f, h0); h1 = fmaf(wv.y, f, h1); h2 = fmaf(wv.z, f, h2);
        }
        h0 += __shfl_xor(h0, 32, 64);
        h1 += __shfl_xor(h1, 32, 64);
        h2 += __shfl_xor(h2, 32, 64);
        if (lane < 32) { pB[w][0][el] = h0; pB[w][1][el] = h1; pB[w][2][el] = h2; }
        __syncthreads();
        if (t < 32) {
            float g0 = pB[0][0][t] + pB[1][0][t] + pB[2][0][t] + pB[3][0][t];
            float g1 = pB[0][1][t] + pB[1][1][t] + pB[2][1][t] + pB[3][1][t];
            float g2 = pB[0][2][t] + pB[1][2][t] + pB[2][2][t] + pB[3][2][t];
            float sq = g0 * g0 + g1 * g1 + g2 * g2;
            float scale = sq / (1.f + sq) / sqrtf(sq + 1e-9f);
            g0 *= scale; g1 *= scale; g2 *= scale;
            if (iter == 2) {
                size_t o = (size_t)b * 3 * DOUT + qr * 32 + t;
                out[o] = g0; out[o + DOUT] = g1; out[o + 2 * DOUT] = g2;
            } else { sH[0][t] = g0; sH[1][t] = g1; sH[2][t] = g2; }
        }
        __syncthreads();
    };
    auto CORE_C = [&](const unsigned* sb, int tau) {
        if (iter == 2) return;
        if (t < SEQ) {
            const int l = t;
            float d0 = 0.f, d1 = 0.f, d2 = 0.f;
#pragma unroll
            for (int j = 0; j < 8; ++j) {
                const int jj = (j + (l & 7) + (l >> 3)) & 7;   // bank-uniform rotation
                uint4 u = *(const uint4*)&sb[(l >> 3) * GSTR + (l & 7) * 32 + 4 * jj];
                float4 x0 = *(const float4*)&sH[0][4 * jj];
                float4 x1 = *(const float4*)&sH[1][4 * jj];
                float4 x2 = *(const float4*)&sH[2][4 * jj];
                float f0 = unpk(u.x), f1 = unpk(u.y), f2 = unpk(u.z), f3 = unpk(u.w);
                d0 += x0.x * f0 + x0.y * f1 + x0.z * f2 + x0.w * f3;
                d1 += x1.x * f0 + x1.y * f1 + x1.z * f2 + x1.w * f3;
                d2 += x2.x * f0 + x2.y * f1 + x2.z * f2 + x2.w * f3;
            }
            float* pp = part + (size_t)tau * PSTR;
            pp[l] = d0; pp[SEQ + l] = d1; pp[2 * SEQ + l] = d2;
        }
    };

    const int tau0 = blockIdx.x, tau1 = blockIdx.x + 2048;
    const int b0 = tau0 >> 2, q0 = tau0 & 3;
    const int b1 = tau1 >> 2, q1 = tau1 & 3;

    RAW(b0);
    STAGE(b0, q0, sLn[0]);
    FIN(b0);                      // waits only its own raws (issued first)
    __syncthreads();              // drains buf0 stage
    CORE_BH(sLn[0], b0, q0);      // internal barriers see no outstanding asyncs
    RAW(b1);
    STAGE(b1, q1, sLn[1]);        // prefetch next task during pass C + softmax
    CORE_C(sLn[0], tau0);
    FIN(b1);
    __syncthreads();              // drains buf1 (had pass C + softmax to land)
    CORE_BH(sLn[1], b1, q1);
    CORE_C(sLn[1], tau1);
}

// ---- K3: contiguous band reduce, 128 blocks x 32 rows; 600 atomics/block ----
__global__ __launch_bounds__(256) void k_reduce(const float* __restrict__ part,
                                                float* __restrict__ accN) {
    const int t = threadIdx.x;
    const int r0 = blockIdx.x * 32;
    if (t < 150) {
        float sx = 0.f, sy = 0.f, sz = 0.f, sw = 0.f;
        for (int r = 0; r < 32; ++r) {
            float4 v = *(const float4*)&part[(size_t)(r0 + r) * PSTR + t * 4];
            sx += v.x; sy += v.y; sz += v.z; sw += v.w;
        }
        atomicAdd(&accN[4 * t + 0], sx);
        atomicAdd(&accN[4 * t + 1], sy);
        atomicAdd(&accN[4 * t + 2], sz);
        atomicAdd(&accN[4 * t + 3], sw);
    }
}

extern "C" void kernel_launch(void* const* d_in, const int* in_sizes, int n_in,
                              void* d_out, int out_size, void* d_ws, size_t ws_size,
                              hipStream_t stream) {
    const float* low_capsule = (const float*)d_in[0];   // [1024][200][128]
    const float* B_matrix    = (const float*)d_in[1];   // [1][3][200]
    const float* S_matrix    = (const float*)d_in[2];   // [128][128]
    const int*   seq_len     = (const int*)d_in[3];     // [1024]
    float* out = (float*)d_out;                         // [1024][3][128]

    unsigned* lowp = (unsigned*)d_ws;                              // 26,214,400 u32
    short* Sp      = (short*)(lowp + (size_t)BATCH * SEQ * DOUT);  // 32768 shorts
    float* acc0    = (float*)(Sp + 32768);                         // 600 (pad 640)
    float* acc1    = acc0 + 640;                                   // 600 (pad 640)
    float* part    = acc1 + 640;                                   // 4096 * PSTR

    hipMemsetAsync(acc0, 0, 1280 * sizeof(float), stream);

    k_presplit<<<64, 256, 0, stream>>>(S_matrix, Sp);
    k_gemm<<<512, 256, 0, stream>>>(low_capsule, Sp, lowp);

    k_iter<<<2048, 256, 0, stream>>>(lowp, B_matrix, seq_len, acc0, acc1, part, out, 0);
    k_reduce<<<128, 256, 0, stream>>>(part, acc0);
    k_iter<<<2048, 256, 0, stream>>>(lowp, B_matrix, seq_len, acc0, acc1, part, out, 1);
    k_reduce<<<128, 256, 0, stream>>>(part, acc1);
    k_iter<<<2048, 256, 0, stream>>>(lowp, B_matrix, seq_len, acc0, acc1, part, out, 2);
}

// Round 8
// 285.511 us; speedup vs baseline: 1.3023x; 1.3023x over previous
//
#include <hip/hip_runtime.h>
#include <math.h>

#define BATCH 1024
#define SEQ   200
#define DIN   128
#define DOUT  128
#define GSTR  260    // k_iter LDS u32 stride per 8-row group (256 data + 4 pad)
#define PSTR  608    // partial-delta row stride (floats)

typedef __attribute__((ext_vector_type(8))) short short8;
typedef __attribute__((ext_vector_type(4))) float f32x4;

// async global->LDS, 16B per lane; LDS dest = wave-uniform base + lane*16
__device__ __forceinline__ void async_copy16(const void* g, void* l) {
    __builtin_amdgcn_global_load_lds((const __attribute__((address_space(1))) void*)g,
                                     (__attribute__((address_space(3))) void*)l,
                                     16, 0, 0);
}

// fp32 -> packed (bf16_hi << 16) | bf16_lo ; hi = round-half-up, lo = RTZ residual
__device__ __forceinline__ unsigned pack_split(float f) {
    unsigned u = __float_as_uint(f);
    unsigned r = u + 0x8000u;
    unsigned hi = r >> 16;
    float hf = __uint_as_float(r & 0xffff0000u);
    unsigned lo = __float_as_uint(f - hf) >> 16;
    return (hi << 16) | lo;
}

__device__ __forceinline__ void split2(float f, short& h, short& l) {
    unsigned u = __float_as_uint(f);
    unsigned r = u + 0x8000u;
    h = (short)(r >> 16);
    float hf = __uint_as_float(r & 0xffff0000u);
    l = (short)(__float_as_uint(f - hf) >> 16);
}

// exact reconstruction of packed value
__device__ __forceinline__ float unpk(unsigned u) {
    return __uint_as_float(u & 0xffff0000u) + __uint_as_float(u << 16);
}

// ---- pre-split S into MFMA B-fragment order (hi at idx, lo at 16384+idx) ----
__global__ __launch_bounds__(256) void k_presplit(const float* __restrict__ S,
                                                  short* __restrict__ Sp) {
    int g = blockIdx.x * 256 + threadIdx.x;          // 0..16383
    int j = g & 7, lane = (g >> 3) & 63, kt = (g >> 9) & 3, nt = g >> 11;
    int k = kt * 32 + (lane >> 4) * 8 + j;
    int n = nt * 16 + (lane & 15);
    short h, l;
    split2(S[k * DOUT + n], h, l);
    Sp[g] = h;
    Sp[16384 + g] = l;
}

// ---- K1: col-split GEMM. block = 128 rows x 64 cols; 4 blocks/CU ----
// blockIdx: bit0 = col group (adjacent blocks share A rows), rest = row tile
__global__ __launch_bounds__(256, 4) void k_gemm(const float* __restrict__ A,
                                                 const short* __restrict__ Sp,
                                                 unsigned* __restrict__ outp) {
    __shared__ short sSp[16384];   // 32 KB: hi [0..8191], lo [8192..]
    const int t = threadIdx.x;
    const int w = t >> 6, lane = t & 63;
    const int q = lane >> 4, c = lane & 15;
    const int cg = blockIdx.x & 1;
    const long rowb = (long)(blockIdx.x >> 1) * 128 + w * 32;

    // async Sp slice stage: two 16 KB contiguous chunks (nt in [4cg,4cg+4))
    {
        const int g = w * 4;   // 16 insts of 1 KB: 4 per wave per half
#pragma unroll
        for (int i = 0; i < 4; ++i) {
            async_copy16(Sp + cg * 8192 + (g + i) * 512 + lane * 8,
                         &sSp[(g + i) * 512]);
            async_copy16(Sp + 16384 + cg * 8192 + (g + i) * 512 + lane * 8,
                         &sSp[8192 + (g + i) * 512]);
        }
    }

    f32x4 acc[2][4];
    const f32x4 zz = {0.f, 0.f, 0.f, 0.f};
#pragma unroll
    for (int mt = 0; mt < 2; ++mt)
#pragma unroll
        for (int nt = 0; nt < 4; ++nt) acc[mt][nt] = zz;

    float4 buf[2][2][2];   // [parity][mt][half] rolling A window
    auto LOADKT = [&](int kt, int p) {
#pragma unroll
        for (int mt = 0; mt < 2; ++mt) {
            const float* ap = A + (rowb + mt * 16 + c) * DIN + kt * 32 + q * 8;
            buf[p][mt][0] = *(const float4*)ap;
            buf[p][mt][1] = *(const float4*)(ap + 4);
        }
    };
    LOADKT(0, 0);
    LOADKT(1, 1);
    __syncthreads();   // drains async Sp stage

#pragma unroll
    for (int kt = 0; kt < 4; ++kt) {
        const int p = kt & 1;
        short8 ah[2], al[2];
#pragma unroll
        for (int mt = 0; mt < 2; ++mt) {
            float av[8];
            *(float4*)&av[0] = buf[p][mt][0];
            *(float4*)&av[4] = buf[p][mt][1];
#pragma unroll
            for (int j = 0; j < 8; ++j) {
                short h, l;
                split2(av[j], h, l);
                ah[mt][j] = h; al[mt][j] = l;
            }
        }
        if (kt < 2) LOADKT(kt + 2, p);   // prefetch 2 ahead into freed parity
#pragma unroll
        for (int nt = 0; nt < 4; ++nt) {
            const int fo = ((nt * 4 + kt) * 64 + lane) * 8;
            short8 sh = *(const short8*)&sSp[fo];
            short8 sl = *(const short8*)&sSp[8192 + fo];
#pragma unroll
            for (int mt = 0; mt < 2; ++mt) {
                acc[mt][nt] = __builtin_amdgcn_mfma_f32_16x16x32_bf16(ah[mt], sh, acc[mt][nt], 0, 0, 0);
                acc[mt][nt] = __builtin_amdgcn_mfma_f32_16x16x32_bf16(al[mt], sh, acc[mt][nt], 0, 0, 0);
                acc[mt][nt] = __builtin_amdgcn_mfma_f32_16x16x32_bf16(ah[mt], sl, acc[mt][nt], 0, 0, 0);
            }
        }
    }
    // C/D: col = lane&15, row = (lane>>4)*4 + r
#pragma unroll
    for (int mt = 0; mt < 2; ++mt)
#pragma unroll
        for (int nt = 0; nt < 4; ++nt) {
            const long r0 = rowb + mt * 16 + q * 4;
            const int col = cg * 64 + nt * 16 + c;
#pragma unroll
            for (int r = 0; r < 4; ++r)
                outp[(r0 + r) * DOUT + col] = pack_split(acc[mt][nt][r]);
        }
}

// ---- K2: routing iteration; block = one (b, e-quarter) task; 5 blocks/CU ----
__global__ __launch_bounds__(256, 5) void k_iter(
    const unsigned* __restrict__ lowp,   // [B][200][128] packed hi|lo
    const float* __restrict__ Bm,        // [3][200]
    const int* __restrict__ seq,         // [B]
    const float* __restrict__ acc0, const float* __restrict__ acc1,
    float* __restrict__ part,            // [4096][PSTR]
    float* __restrict__ out, int iter) {
    __shared__ unsigned sLn[25 * GSTR];  // 26 KB, 8-row groups (+4 pad)
    __shared__ float sW[SEQ * 4];
    __shared__ float pB[4][3][32];
    __shared__ float sH[3][32];

    const int t = threadIdx.x, lane = t & 63, w = t >> 6;
    const int b = blockIdx.x >> 2, qr = blockIdx.x & 3;
    const unsigned* lp = lowp + (size_t)b * (SEQ * DIN) + qr * 32;

    // (1) softmax raw loads first
    float r0[4], r1[4], r2[4];
    if (w < 3) {
#pragma unroll
        for (int i = 0; i < 4; ++i) {
            int l = lane + 64 * i; bool inb = l < SEQ;
            r0[i] = inb ? Bm[w * SEQ + l] : 0.f;
            r1[i] = (inb && iter >= 1) ? acc0[w * SEQ + l] : 0.f;
            r2[i] = (inb && iter >= 2) ? acc1[w * SEQ + l] : 0.f;
        }
    }

    // (2) async stage: 25 x 1KB (8 rows x 32 u32 each)
    for (int g = w; g < 25; g += 4)
        async_copy16(lp + (g * 8 + (lane >> 3)) * DIN + (lane & 7) * 4,
                     &sLn[g * GSTR]);

    // (3) softmax compute
    if (w < 3) {
        const int n = seq[b];
        float m = -INFINITY, vv[4];
#pragma unroll
        for (int i = 0; i < 4; ++i) {
            int l = lane + 64 * i;
            float v = r0[i] + r1[i] + r2[i];
            vv[i] = (l < n) ? v : -INFINITY;
            if (l < n) m = fmaxf(m, v);
        }
        for (int off = 32; off; off >>= 1) m = fmaxf(m, __shfl_xor(m, off, 64));
        float s = 0.f, pv[4];
#pragma unroll
        for (int i = 0; i < 4; ++i) {
            pv[i] = (vv[i] == -INFINITY) ? 0.f : expf(vv[i] - m);
            s += pv[i];
        }
        for (int off = 32; off; off >>= 1) s += __shfl_xor(s, off, 64);
        float rs = 1.f / s;
#pragma unroll
        for (int i = 0; i < 4; ++i) {
            int l = lane + 64 * i;
            if (l < SEQ) sW[l * 4 + w] = pv[i] * rs;
        }
    }
    __syncthreads();   // drains async stage

    // (4) Pass B: h[k][e] over 32 e-cols; 8 l-groups (lane-bit5 x wave)
    {
        const int el = t & 31, lg = t >> 5;
        float h0 = 0.f, h1 = 0.f, h2 = 0.f;
#pragma unroll
        for (int i = 0; i < 25; ++i) {
            int l = lg * 25 + i;
            float4 wv = *(const float4*)&sW[l * 4];
            float f = unpk(sLn[(l >> 3) * GSTR + (l & 7) * 32 + el]);
            h0 = fmaf(wv.x, f, h0); h1 = fmaf(wv.y, f, h1); h2 = fmaf(wv.z, f, h2);
        }
        h0 += __shfl_xor(h0, 32, 64);
        h1 += __shfl_xor(h1, 32, 64);
        h2 += __shfl_xor(h2, 32, 64);
        if (lane < 32) { pB[w][0][el] = h0; pB[w][1][el] = h1; pB[w][2][el] = h2; }
    }
    __syncthreads();

    // (5) cross-wave reduce + squash
    if (t < 32) {
        float g0 = pB[0][0][t] + pB[1][0][t] + pB[2][0][t] + pB[3][0][t];
        float g1 = pB[0][1][t] + pB[1][1][t] + pB[2][1][t] + pB[3][1][t];
        float g2 = pB[0][2][t] + pB[1][2][t] + pB[2][2][t] + pB[3][2][t];
        float sq = g0 * g0 + g1 * g1 + g2 * g2;
        float scale = sq / (1.f + sq) / sqrtf(sq + 1e-9f);
        g0 *= scale; g1 *= scale; g2 *= scale;
        if (iter == 2) {
            size_t o = (size_t)b * 3 * DOUT + qr * 32 + t;
            out[o] = g0; out[o + DOUT] = g1; out[o + 2 * DOUT] = g2;
        } else { sH[0][t] = g0; sH[1][t] = g1; sH[2][t] = g2; }
    }
    if (iter == 2) return;   // uniform exit
    __syncthreads();

    // (6) Pass C: thread = l; 8 rotated 16B chunks
    if (t < SEQ) {
        const int l = t;
        float d0 = 0.f, d1 = 0.f, d2 = 0.f;
#pragma unroll
        for (int j = 0; j < 8; ++j) {
            const int jj = (j + (l & 7) + (l >> 3)) & 7;
            uint4 u = *(const uint4*)&sLn[(l >> 3) * GSTR + (l & 7) * 32 + 4 * jj];
            float4 x0 = *(const float4*)&sH[0][4 * jj];
            float4 x1 = *(const float4*)&sH[1][4 * jj];
            float4 x2 = *(const float4*)&sH[2][4 * jj];
            float f0 = unpk(u.x), f1 = unpk(u.y), f2 = unpk(u.z), f3 = unpk(u.w);
            d0 += x0.x * f0 + x0.y * f1 + x0.z * f2 + x0.w * f3;
            d1 += x1.x * f0 + x1.y * f1 + x1.z * f2 + x1.w * f3;
            d2 += x2.x * f0 + x2.y * f1 + x2.z * f2 + x2.w * f3;
        }
        float* pp = part + (size_t)blockIdx.x * PSTR;
        pp[l] = d0; pp[SEQ + l] = d1; pp[2 * SEQ + l] = d2;
    }
}

// ---- K3: contiguous band reduce, 128 blocks x 32 rows; 600 atomics/block ----
__global__ __launch_bounds__(256) void k_reduce(const float* __restrict__ part,
                                                float* __restrict__ accN) {
    const int t = threadIdx.x;
    const int r0 = blockIdx.x * 32;
    if (t < 150) {
        float sx = 0.f, sy = 0.f, sz = 0.f, sw = 0.f;
        for (int r = 0; r < 32; ++r) {
            float4 v = *(const float4*)&part[(size_t)(r0 + r) * PSTR + t * 4];
            sx += v.x; sy += v.y; sz += v.z; sw += v.w;
        }
        atomicAdd(&accN[4 * t + 0], sx);
        atomicAdd(&accN[4 * t + 1], sy);
        atomicAdd(&accN[4 * t + 2], sz);
        atomicAdd(&accN[4 * t + 3], sw);
    }
}

extern "C" void kernel_launch(void* const* d_in, const int* in_sizes, int n_in,
                              void* d_out, int out_size, void* d_ws, size_t ws_size,
                              hipStream_t stream) {
    const float* low_capsule = (const float*)d_in[0];   // [1024][200][128]
    const float* B_matrix    = (const float*)d_in[1];   // [1][3][200]
    const float* S_matrix    = (const float*)d_in[2];   // [128][128]
    const int*   seq_len     = (const int*)d_in[3];     // [1024]
    float* out = (float*)d_out;                         // [1024][3][128]

    unsigned* lowp = (unsigned*)d_ws;                              // 26,214,400 u32
    short* Sp      = (short*)(lowp + (size_t)BATCH * SEQ * DOUT);  // 32768 shorts
    float* acc0    = (float*)(Sp + 32768);                         // 600 (pad 640)
    float* acc1    = acc0 + 640;                                   // 600 (pad 640)
    float* part    = acc1 + 640;                                   // 4096 * PSTR

    hipMemsetAsync(acc0, 0, 1280 * sizeof(float), stream);

    k_presplit<<<64, 256, 0, stream>>>(S_matrix, Sp);
    k_gemm<<<2 * (BATCH * SEQ) / 128, 256, 0, stream>>>(low_capsule, Sp, lowp);

    k_iter<<<4096, 256, 0, stream>>>(lowp, B_matrix, seq_len, acc0, acc1, part, out, 0);
    k_reduce<<<128, 256, 0, stream>>>(part, acc0);
    k_iter<<<4096, 256, 0, stream>>>(lowp, B_matrix, seq_len, acc0, acc1, part, out, 1);
    k_reduce<<<128, 256, 0, stream>>>(part, acc1);
    k_iter<<<4096, 256, 0, stream>>>(lowp, B_matrix, seq_len, acc0, acc1, part, out, 2);
}